// Round 1
// baseline (3866.362 us; speedup 1.0000x reference)
//
#include <hip/hip_runtime.h>

constexpr int TPB = 256;

__device__ __forceinline__ float lrelu(float x){ return x > 0.f ? x : 0.2f*x; }
// order-preserving float<->unsigned encoding for atomicMax on floats
__device__ __forceinline__ unsigned fenc(float f){
  unsigned u = __float_as_uint(f);
  return (u & 0x80000000u) ? ~u : (u | 0x80000000u);
}
__device__ __forceinline__ float fdec(unsigned u){
  return __uint_as_float((u & 0x80000000u) ? (u & 0x7fffffffu) : ~u);
}

// fold BN eval params into scale/shift per channel; out = [sc1(128), sh1(128), sc2(128), sh2(128)]
__global__ void k_bnfold(const float* __restrict__ g1, const float* __restrict__ b1,
                         const float* __restrict__ m1, const float* __restrict__ v1,
                         const float* __restrict__ g2, const float* __restrict__ b2,
                         const float* __restrict__ m2, const float* __restrict__ v2,
                         float* __restrict__ out){
  int t = threadIdx.x;
  int o = t & 127;
  bool second = t >= 128;
  const float* g = second ? g2 : g1;  const float* b = second ? b2 : b1;
  const float* m = second ? m2 : m1;  const float* v = second ? v2 : v1;
  float sc = g[o] * rsqrtf(v[o] + 1e-5f);
  float sh = b[o] - m[o]*sc;
  int off = second ? 256 : 0;
  out[off + o] = sc;
  out[off + 128 + o] = sh;
}

__global__ void k_count(const int* __restrict__ dst, float* __restrict__ deg, int E){
  int t = blockIdx.x*TPB + threadIdx.x;
  if (t < E) atomicAdd(&deg[dst[t]], 1.f);
}

// agg[dst] += x[src], C channels, one float4 per thread
template<int C>
__global__ void k_scatter(const int* __restrict__ src, const int* __restrict__ dst,
                          const float* __restrict__ x, float* __restrict__ agg, int E){
  constexpr int CV = C/4;
  int t = blockIdx.x*TPB + threadIdx.x;
  if (t >= E*CV) return;
  int e = t / CV;
  int c = (t % CV) * 4;
  int s = src[e], d = dst[e];
  float4 v = *(const float4*)(x + (size_t)s*C + c);
  float* p = agg + (size_t)d*C + c;
  atomicAdd(p+0, v.x); atomicAdd(p+1, v.y);
  atomicAdd(p+2, v.z); atomicAdd(p+3, v.w);
}

// out[g,:] = epilogue( mean(agg[g])/deg @ wl + bias + xr[g] @ wr ), COUT=128 fixed.
// 16 nodes per 256-thread block; weights staged through LDS in 64-row K-chunks.
template<int CIN, bool HAS_AGG, bool BN, bool RES, bool RELU>
__global__ __launch_bounds__(256) void k_node_mm(
    const float* __restrict__ xr, const float* __restrict__ agg,
    const float* __restrict__ deg,
    const float* __restrict__ wl, const float* __restrict__ wr,
    const float* __restrict__ bias,
    const float* __restrict__ bnsc, const float* __restrict__ bnsh,
    const float* __restrict__ res,
    float* __restrict__ out, int n)
{
  constexpr int NB = 16;     // nodes per block
  constexpr int CO = 128;    // output channels
  __shared__ float sWr[64][CO];
  __shared__ float sWl[HAS_AGG ? 64 : 1][HAS_AGG ? CO : 1];
  __shared__ float sX[NB][CIN];
  __shared__ float sM[HAS_AGG ? NB : 1][HAS_AGG ? CIN : 1];
  int tid = threadIdx.x;
  int node0 = blockIdx.x * NB;

  // stage node features (x and mean = agg/deg)
  for (int idx = tid; idx < NB*CIN/4; idx += 256) {
    int p = idx * 4;
    int nl = p / CIN, c = p % CIN;
    int g = node0 + nl;
    float4 xv = make_float4(0.f,0.f,0.f,0.f);
    float4 mv = make_float4(0.f,0.f,0.f,0.f);
    if (g < n) {
      xv = *(const float4*)(xr + (size_t)g*CIN + c);
      if constexpr (HAS_AGG) {
        float id = 1.f / fmaxf(deg[g], 1.f);
        float4 a = *(const float4*)(agg + (size_t)g*CIN + c);
        mv = make_float4(a.x*id, a.y*id, a.z*id, a.w*id);
      }
    }
    *(float4*)&sX[nl][c] = xv;
    if constexpr (HAS_AGG) *(float4*)&sM[nl][c] = mv;
  }

  float acc[NB/2];
  #pragma unroll
  for (int i = 0; i < NB/2; ++i) acc[i] = 0.f;
  int o    = tid & 127;
  int half = tid >> 7;

  for (int kc = 0; kc < CIN; kc += 64) {
    __syncthreads();
    for (int idx = tid; idx < 64*CO/4; idx += 256) {
      int p = idx * 4;
      int k = p / CO, oo = p % CO;
      *(float4*)&sWr[k][oo] = *(const float4*)(wr + (size_t)(kc+k)*CO + oo);
      if constexpr (HAS_AGG)
        *(float4*)&sWl[k][oo] = *(const float4*)(wl + (size_t)(kc+k)*CO + oo);
    }
    __syncthreads();
    #pragma unroll 4
    for (int k = 0; k < 64; ++k) {
      float wrv = sWr[k][o];
      float wlv = HAS_AGG ? sWl[k][o] : 0.f;
      int c = kc + k;
      #pragma unroll
      for (int ni = 0; ni < NB/2; ++ni) {
        int node = ni*2 + half;
        acc[ni] = fmaf(sX[node][c], wrv, acc[ni]);
        if constexpr (HAS_AGG) acc[ni] = fmaf(sM[node][c], wlv, acc[ni]);
      }
    }
  }

  float bv = 0.f;
  if (bias) bv = bias[o];
  float sc = 1.f, sh = 0.f;
  if constexpr (BN) { sc = bnsc[o]; sh = bnsh[o]; }
  #pragma unroll
  for (int ni = 0; ni < NB/2; ++ni) {
    int node = ni*2 + half;
    int g = node0 + node;
    if (g < n) {
      float v = acc[ni] + bv;
      if constexpr (BN)   v = v*sc + sh;
      if constexpr (RES)  v += res[(size_t)g*CO + o];
      if constexpr (RELU) v = fmaxf(v, 0.f);
      out[(size_t)g*CO + o] = v;
    }
  }
}

// per (node, head): a_src/a_dst attention scalars
__global__ void k_attn(const float* __restrict__ hg, const float* __restrict__ atts,
                       const float* __restrict__ attd, float* __restrict__ asrc,
                       float* __restrict__ adst, int n){
  int t = blockIdx.x*TPB + threadIdx.x;
  if (t >= n*4) return;
  int nid = t >> 2, h = t & 3;
  const float* hp = hg + (size_t)nid*128 + h*32;
  float as = 0.f, ad = 0.f;
  #pragma unroll
  for (int c = 0; c < 32; ++c) {
    float v = hp[c];
    as = fmaf(v, atts[h*32+c], as);
    ad = fmaf(v, attd[h*32+c], ad);
  }
  asrc[t] = as; adst[t] = ad;
}

// init running max with the self-loop attention value (every node has one)
__global__ void k_self_init(const float* __restrict__ asrc, const float* __restrict__ adst,
                            unsigned* __restrict__ menc, int n){
  int t = blockIdx.x*TPB + threadIdx.x;
  if (t >= n*4) return;
  menc[t] = fenc(lrelu(asrc[t] + adst[t]));
}

__global__ void k_edge_max(const int* __restrict__ src, const int* __restrict__ dst,
                           const float* __restrict__ asrc, const float* __restrict__ adst,
                           unsigned* __restrict__ menc, int E){
  int t = blockIdx.x*TPB + threadIdx.x;
  if (t >= E) return;
  int s = src[t], d = dst[t];
  #pragma unroll
  for (int h = 0; h < 4; ++h) {
    unsigned v = fenc(lrelu(asrc[s*4+h] + adst[d*4+h]));
    atomicMax(&menc[d*4+h], v);
  }
}

// self-loop contribution: num = ex_self * hg, den = ex_self (plain stores, runs before edge accum)
__global__ void k_self_sm(const float* __restrict__ asrc, const float* __restrict__ adst,
                          const unsigned* __restrict__ menc, const float* __restrict__ hg,
                          float* __restrict__ num, float* __restrict__ den, int n){
  int t = blockIdx.x*TPB + threadIdx.x;
  if (t >= n*128) return;
  int nid = t >> 7, o = t & 127, h = o >> 5;
  float m = fdec(menc[nid*4+h]);
  float e = lrelu(asrc[nid*4+h] + adst[nid*4+h]);
  float ex = expf(e - m);
  num[t] = ex * hg[t];
  if ((o & 31) == 0) den[nid*4+h] = ex;
}

__global__ void k_edge_den(const int* __restrict__ src, const int* __restrict__ dst,
                           const float* __restrict__ asrc, const float* __restrict__ adst,
                           const unsigned* __restrict__ menc, float* __restrict__ exf,
                           float* __restrict__ den, int E){
  int t = blockIdx.x*TPB + threadIdx.x;
  if (t >= E*4) return;
  int e = t >> 2, h = t & 3;
  int s = src[e], d = dst[e];
  float ev = lrelu(asrc[s*4+h] + adst[d*4+h]);
  float ex = expf(ev - fdec(menc[d*4+h]));
  exf[t] = ex;
  atomicAdd(&den[d*4+h], ex);
}

__global__ void k_edge_num(const int* __restrict__ src, const int* __restrict__ dst,
                           const float* __restrict__ exf, const float* __restrict__ hg,
                           float* __restrict__ num, int E){
  int t = blockIdx.x*TPB + threadIdx.x;
  if (t >= E*32) return;
  int e = t >> 5, o4 = t & 31;
  int o = o4 * 4, h = o4 >> 3;
  int s = src[e], d = dst[e];
  float ex = exf[e*4+h];
  float4 v = *(const float4*)(hg + (size_t)s*128 + o);
  float* p = num + (size_t)d*128 + o;
  atomicAdd(p+0, ex*v.x); atomicAdd(p+1, ex*v.y);
  atomicAdd(p+2, ex*v.z); atomicAdd(p+3, ex*v.w);
}

// head-mean + gat bias -> embeddings; then 32->64 relu -> 1 classifier
__global__ void k_final(const float* __restrict__ num, const float* __restrict__ den,
                        const float* __restrict__ gbias,
                        const float* __restrict__ w1, const float* __restrict__ b1,
                        const float* __restrict__ w2, const float* __restrict__ b2,
                        float* __restrict__ out_emb, float* __restrict__ out_log, int n){
  int nid = blockIdx.x*TPB + threadIdx.x;
  if (nid >= n) return;
  float inv[4];
  #pragma unroll
  for (int h = 0; h < 4; ++h) inv[h] = 1.f / den[nid*4+h];
  float emb[32];
  #pragma unroll
  for (int c = 0; c < 32; ++c) {
    float v = 0.f;
    #pragma unroll
    for (int h = 0; h < 4; ++h) v = fmaf(num[(size_t)nid*128 + h*32 + c], inv[h], v);
    emb[c] = 0.25f * v + gbias[c];
    out_emb[(size_t)nid*32 + c] = emb[c];
  }
  float logit = b2[0];
  for (int j = 0; j < 64; ++j) {
    float a = b1[j];
    #pragma unroll
    for (int c = 0; c < 32; ++c) a = fmaf(emb[c], w1[c*64 + j], a);
    logit = fmaf(fmaxf(a, 0.f), w2[j], logit);
  }
  out_log[nid] = logit;
}

extern "C" void kernel_launch(void* const* d_in, const int* in_sizes, int n_in,
                              void* d_out, int out_size, void* d_ws, size_t ws_size,
                              hipStream_t stream) {
  const float* x    = (const float*)d_in[0];
  const int*   ei   = (const int*)  d_in[1];
  const float* s1wl = (const float*)d_in[2];
  const float* s1bl = (const float*)d_in[3];
  const float* s1wr = (const float*)d_in[4];
  const float* bn1g = (const float*)d_in[5];
  const float* bn1b = (const float*)d_in[6];
  const float* bn1m = (const float*)d_in[7];
  const float* bn1v = (const float*)d_in[8];
  const float* s2wl = (const float*)d_in[9];
  const float* s2bl = (const float*)d_in[10];
  const float* s2wr = (const float*)d_in[11];
  const float* bn2g = (const float*)d_in[12];
  const float* bn2b = (const float*)d_in[13];
  const float* bn2m = (const float*)d_in[14];
  const float* bn2v = (const float*)d_in[15];
  const float* gatw = (const float*)d_in[16];
  const float* atts = (const float*)d_in[17];
  const float* attd = (const float*)d_in[18];
  const float* gatb = (const float*)d_in[19];
  const float* cw1  = (const float*)d_in[20];
  const float* cb1  = (const float*)d_in[21];
  const float* cw2  = (const float*)d_in[22];
  const float* cb2  = (const float*)d_in[23];

  const int N = in_sizes[0] / 64;
  const int E = in_sizes[1] / 2;
  const int* src = ei;
  const int* dst = ei + E;

  // workspace layout (lifetime-aliased): peak ~90 MB
  float* W    = (float*)d_ws;
  float* deg  = W;                              // [N]
  float* bnp  = W + N;                          // [512]
  float* base = bnp + 512;
  float* agg1 = base;                           // [N*64]   (SAGE1)
  float* h1   = base + (size_t)N*64;            // [N*128]
  float* agg2 = base + (size_t)N*192;           // [N*128]  (SAGE2)
  float* h2   = base + (size_t)N*320;           // [N*128]
  // GAT phase aliases (agg1/h1/agg2 dead by then):
  float* hg   = base;                           // [N*128]  h2 @ gat_w
  float* num  = base + (size_t)N*128;           // [N*128]
  float* asrc = base + (size_t)N*256;           // [N*4]
  float* adst = asrc + (size_t)N*4;             // [N*4]
  float* den  = adst + (size_t)N*4;             // [N*4]
  unsigned* menc = (unsigned*)(den + (size_t)N*4); // [N*4]
  float* exf  = h2;                             // [E*4]    (h2 dead after gat mm)

  float* out_emb = (float*)d_out;
  float* out_log = out_emb + (size_t)N*32;

  hipMemsetAsync(deg,  0, (size_t)N*4,      stream);
  hipMemsetAsync(agg1, 0, (size_t)N*64*4,   stream);
  hipMemsetAsync(agg2, 0, (size_t)N*128*4,  stream);

  k_bnfold<<<1, 256, 0, stream>>>(bn1g,bn1b,bn1m,bn1v, bn2g,bn2b,bn2m,bn2v, bnp);
  k_count<<<(E+TPB-1)/TPB, TPB, 0, stream>>>(dst, deg, E);

  k_scatter<64><<<(E*16+TPB-1)/TPB, TPB, 0, stream>>>(src, dst, x, agg1, E);
  int nmb = (N + 15) / 16;
  k_node_mm<64,true,true,false,true><<<nmb, 256, 0, stream>>>(
      x, agg1, deg, s1wl, s1wr, s1bl, bnp, bnp+128, nullptr, h1, N);

  k_scatter<128><<<(E*32+TPB-1)/TPB, TPB, 0, stream>>>(src, dst, h1, agg2, E);
  k_node_mm<128,true,true,true,true><<<nmb, 256, 0, stream>>>(
      h1, agg2, deg, s2wl, s2wr, s2bl, bnp+256, bnp+384, h1, h2, N);

  k_node_mm<128,false,false,false,false><<<nmb, 256, 0, stream>>>(
      h2, nullptr, nullptr, nullptr, gatw, nullptr, nullptr, nullptr, nullptr, hg, N);

  k_attn<<<(N*4+TPB-1)/TPB, TPB, 0, stream>>>(hg, atts, attd, asrc, adst, N);
  k_self_init<<<(N*4+TPB-1)/TPB, TPB, 0, stream>>>(asrc, adst, menc, N);
  k_edge_max<<<(E+TPB-1)/TPB, TPB, 0, stream>>>(src, dst, asrc, adst, menc, E);
  k_self_sm<<<(N*128+TPB-1)/TPB, TPB, 0, stream>>>(asrc, adst, menc, hg, num, den, N);
  k_edge_den<<<(E*4+TPB-1)/TPB, TPB, 0, stream>>>(src, dst, asrc, adst, menc, exf, den, E);
  k_edge_num<<<(E*32+TPB-1)/TPB, TPB, 0, stream>>>(src, dst, exf, hg, num, E);

  k_final<<<(N+TPB-1)/TPB, TPB, 0, stream>>>(
      num, den, gatb, cw1, cb1, cw2, cb2, out_emb, out_log, N);
}

// Round 2
// 783.744 us; speedup vs baseline: 4.9332x; 4.9332x over previous
//
#include <hip/hip_runtime.h>

constexpr int TPB = 256;

__device__ __forceinline__ float lrelu(float x){ return x > 0.f ? x : 0.2f*x; }

// fold BN eval params into scale/shift per channel; out = [sc1(128), sh1(128), sc2(128), sh2(128)]
__global__ void k_bnfold(const float* __restrict__ g1, const float* __restrict__ b1,
                         const float* __restrict__ m1, const float* __restrict__ v1,
                         const float* __restrict__ g2, const float* __restrict__ b2,
                         const float* __restrict__ m2, const float* __restrict__ v2,
                         float* __restrict__ out){
  int t = threadIdx.x;
  int o = t & 127;
  bool second = t >= 128;
  const float* g = second ? g2 : g1;  const float* b = second ? b2 : b1;
  const float* m = second ? m2 : m1;  const float* v = second ? v2 : v1;
  float sc = g[o] * rsqrtf(v[o] + 1e-5f);
  float sh = b[o] - m[o]*sc;
  int off = second ? 256 : 0;
  out[off + o] = sc;
  out[off + 128 + o] = sh;
}

// ---------------- CSR build ----------------
__global__ void k_deg(const int* __restrict__ dst, int* __restrict__ degi, int E){
  int t = blockIdx.x*TPB + threadIdx.x;
  if (t < E) atomicAdd(&degi[dst[t]], 1);
}

// single-block exclusive scan over n elements (n ~ 50000)
__global__ void k_scan(const int* __restrict__ deg, int* __restrict__ offs, int n){
  __shared__ int sh[1024];
  __shared__ int carry;
  int tid = threadIdx.x;
  if (tid == 0) carry = 0;
  __syncthreads();
  for (int base = 0; base < n; base += 1024){
    int i = base + tid;
    int v = (i < n) ? deg[i] : 0;
    sh[tid] = v;
    __syncthreads();
    int val = v;
    for (int off = 1; off < 1024; off <<= 1){
      int t = (tid >= off) ? sh[tid - off] : 0;
      __syncthreads();
      val += t;
      sh[tid] = val;
      __syncthreads();
    }
    int c = carry;
    if (i < n) offs[i] = c + val - v;
    __syncthreads();
    if (tid == 1023) carry = c + sh[1023];
    __syncthreads();
  }
  if (tid == 0) offs[n] = carry;
}

__global__ void k_fill(const int* __restrict__ src, const int* __restrict__ dst,
                       const int* __restrict__ offs, int* __restrict__ cur,
                       int* __restrict__ esrc, int E){
  int t = blockIdx.x*TPB + threadIdx.x;
  if (t >= E) return;
  int d = dst[t];
  int p = offs[d] + atomicAdd(&cur[d], 1);
  esrc[p] = src[t];
}

// ---------------- mean aggregation via gather ----------------
// C threads per node; each lane owns one channel, loops the node's edge list.
template<int C>
__global__ __launch_bounds__(256) void k_gather_mean(
    const int* __restrict__ offs, const int* __restrict__ esrc,
    const float* __restrict__ x, float* __restrict__ mean, int n){
  constexpr int NPB = 256 / C;
  int tid = threadIdx.x;
  int nl = tid / C, c = tid % C;
  int nid = blockIdx.x*NPB + nl;
  if (nid >= n) return;
  int k0 = offs[nid], k1 = offs[nid+1];
  float sum = 0.f;
  for (int k = k0; k < k1; ++k){
    int s = esrc[k];
    sum += x[(size_t)s*C + c];
  }
  float inv = 1.f / (float)max(k1 - k0, 1);
  mean[(size_t)nid*C + c] = sum * inv;
}

// ---------------- node matmul: out = mean@wl + bias + x@wr, epilogue fused ----------------
// 16 nodes/block, 256 threads; thread owns node nl=tid>>4 and output quads o4, o4+64.
template<int CIN, bool HAS_MEAN, bool BN, bool RES, bool RELU>
__global__ __launch_bounds__(256) void k_node_mm(
    const float* __restrict__ xr, const float* __restrict__ mean,
    const float* __restrict__ wl, const float* __restrict__ wr,
    const float* __restrict__ bias,
    const float* __restrict__ bnp, int bnoff,
    const float* __restrict__ res,
    float* __restrict__ out, int n)
{
  constexpr int NB = 16;
  constexpr int CO = 128;
  constexpr int CP = CIN + 4;   // pad: (CP % 32 == 4) -> node rows land in distinct banks
  constexpr int KCH = 32;       // K-chunk for weight staging (keeps LDS ~<50KB -> 3 blocks/CU)
  __shared__ float sWr[KCH][CO];
  __shared__ float sWl[HAS_MEAN ? KCH : 1][HAS_MEAN ? CO : 1];
  __shared__ float sX[NB][CP];
  __shared__ float sM[HAS_MEAN ? NB : 1][HAS_MEAN ? CP : 1];
  int tid = threadIdx.x;
  int node0 = blockIdx.x * NB;
  int nl = tid >> 4;
  int o4 = (tid & 15) * 4;

  // stage node features once
  for (int idx = tid; idx < NB*CIN/4; idx += 256) {
    int p = idx * 4;
    int node = p / CIN, c = p % CIN;
    int g = node0 + node;
    float4 xv = make_float4(0.f,0.f,0.f,0.f);
    float4 mv = make_float4(0.f,0.f,0.f,0.f);
    if (g < n){
      xv = *(const float4*)(xr + (size_t)g*CIN + c);
      if constexpr (HAS_MEAN) mv = *(const float4*)(mean + (size_t)g*CIN + c);
    }
    *(float4*)&sX[node][c] = xv;
    if constexpr (HAS_MEAN) *(float4*)&sM[node][c] = mv;
  }

  float accA[4] = {0,0,0,0};
  float accB[4] = {0,0,0,0};

  for (int kc = 0; kc < CIN; kc += KCH) {
    __syncthreads();
    for (int idx = tid; idx < KCH*CO/4; idx += 256) {
      int p = idx * 4;
      int k = p / CO, oo = p % CO;
      *(float4*)&sWr[k][oo] = *(const float4*)(wr + (size_t)(kc+k)*CO + oo);
      if constexpr (HAS_MEAN)
        *(float4*)&sWl[k][oo] = *(const float4*)(wl + (size_t)(kc+k)*CO + oo);
    }
    __syncthreads();
    #pragma unroll
    for (int k = 0; k < KCH; ++k) {
      float xv = sX[nl][kc + k];
      float4 wra = *(const float4*)&sWr[k][o4];
      float4 wrb = *(const float4*)&sWr[k][o4 + 64];
      accA[0] = fmaf(xv, wra.x, accA[0]);
      accA[1] = fmaf(xv, wra.y, accA[1]);
      accA[2] = fmaf(xv, wra.z, accA[2]);
      accA[3] = fmaf(xv, wra.w, accA[3]);
      accB[0] = fmaf(xv, wrb.x, accB[0]);
      accB[1] = fmaf(xv, wrb.y, accB[1]);
      accB[2] = fmaf(xv, wrb.z, accB[2]);
      accB[3] = fmaf(xv, wrb.w, accB[3]);
      if constexpr (HAS_MEAN) {
        float mv = sM[nl][kc + k];
        float4 wla = *(const float4*)&sWl[k][o4];
        float4 wlb = *(const float4*)&sWl[k][o4 + 64];
        accA[0] = fmaf(mv, wla.x, accA[0]);
        accA[1] = fmaf(mv, wla.y, accA[1]);
        accA[2] = fmaf(mv, wla.z, accA[2]);
        accA[3] = fmaf(mv, wla.w, accA[3]);
        accB[0] = fmaf(mv, wlb.x, accB[0]);
        accB[1] = fmaf(mv, wlb.y, accB[1]);
        accB[2] = fmaf(mv, wlb.z, accB[2]);
        accB[3] = fmaf(mv, wlb.w, accB[3]);
      }
    }
  }

  int g = node0 + nl;
  if (g < n) {
    float* accs[2] = {accA, accB};
    #pragma unroll
    for (int q = 0; q < 2; ++q) {
      int o = o4 + q*64;
      float4 v;
      float* a = accs[q];
      float vv[4];
      #pragma unroll
      for (int j = 0; j < 4; ++j) {
        float t = a[j];
        if (bias) t += bias[o + j];
        if constexpr (BN) t = t * bnp[bnoff + o + j] + bnp[bnoff + 128 + o + j];
        vv[j] = t;
      }
      if constexpr (RES) {
        float4 rv = *(const float4*)(res + (size_t)g*CO + o);
        vv[0] += rv.x; vv[1] += rv.y; vv[2] += rv.z; vv[3] += rv.w;
      }
      if constexpr (RELU) {
        vv[0] = fmaxf(vv[0], 0.f); vv[1] = fmaxf(vv[1], 0.f);
        vv[2] = fmaxf(vv[2], 0.f); vv[3] = fmaxf(vv[3], 0.f);
      }
      v = make_float4(vv[0], vv[1], vv[2], vv[3]);
      *(float4*)(out + (size_t)g*CO + o) = v;
    }
  }
}

// ---------------- GAT ----------------
__global__ void k_attn(const float* __restrict__ hg, const float* __restrict__ atts,
                       const float* __restrict__ attd, float* __restrict__ asrc,
                       float* __restrict__ adst, int n){
  int t = blockIdx.x*TPB + threadIdx.x;
  if (t >= n*4) return;
  int nid = t >> 2, h = t & 3;
  const float* hp = hg + (size_t)nid*128 + h*32;
  float as = 0.f, ad = 0.f;
  #pragma unroll
  for (int c = 0; c < 32; ++c) {
    float v = hp[c];
    as = fmaf(v, atts[h*32+c], as);
    ad = fmaf(v, attd[h*32+c], ad);
  }
  asrc[t] = as; adst[t] = ad;
}

// per (node,head) max over {self} U incoming edges
__global__ void k_gat_max(const int* __restrict__ offs, const int* __restrict__ esrc,
                          const float* __restrict__ asrc, const float* __restrict__ adst,
                          float* __restrict__ mmax, int n){
  int t = blockIdx.x*TPB + threadIdx.x;
  if (t >= n*4) return;
  int nid = t >> 2, h = t & 3;
  float ad = adst[t];
  float m = lrelu(asrc[t] + ad);   // self-loop
  int k0 = offs[nid], k1 = offs[nid+1];
  for (int k = k0; k < k1; ++k){
    int s = esrc[k];
    m = fmaxf(m, lrelu(asrc[s*4+h] + ad));
  }
  mmax[t] = m;
}

// fused: softmax-weighted gather + normalize + head-mean + bias -> embeddings
__global__ __launch_bounds__(256) void k_gat(
    const int* __restrict__ offs, const int* __restrict__ esrc,
    const float* __restrict__ asrc, const float* __restrict__ adst,
    const float* __restrict__ mmax, const float* __restrict__ hg,
    const float* __restrict__ gbias, float* __restrict__ out_emb, int n){
  __shared__ float sval[2][128];
  int tid = threadIdx.x;
  int nl = tid >> 7, c = tid & 127;
  int h = c >> 5;
  int nid = blockIdx.x*2 + nl;
  bool act = nid < n;
  if (act){
    int i4 = nid*4 + h;
    float ad = adst[i4];
    float m  = mmax[i4];
    float ex = expf(lrelu(asrc[i4] + ad) - m);   // self
    float accD = ex;
    float accN = ex * hg[(size_t)nid*128 + c];
    int k0 = offs[nid], k1 = offs[nid+1];
    for (int k = k0; k < k1; ++k){
      int s = esrc[k];
      float e = expf(lrelu(asrc[s*4+h] + ad) - m);
      accD += e;
      accN += e * hg[(size_t)s*128 + c];
    }
    sval[nl][c] = accN / accD;
  }
  __syncthreads();
  if (act && c < 32){
    float e = 0.25f*(sval[nl][c] + sval[nl][c+32] + sval[nl][c+64] + sval[nl][c+96]) + gbias[c];
    out_emb[(size_t)nid*32 + c] = e;
  }
}

// classifier MLP
__global__ void k_final(const float* __restrict__ emb,
                        const float* __restrict__ w1, const float* __restrict__ b1,
                        const float* __restrict__ w2, const float* __restrict__ b2,
                        float* __restrict__ out_log, int n){
  int nid = blockIdx.x*TPB + threadIdx.x;
  if (nid >= n) return;
  float e[32];
  #pragma unroll
  for (int c = 0; c < 32; ++c) e[c] = emb[(size_t)nid*32 + c];
  float logit = b2[0];
  for (int j = 0; j < 64; ++j) {
    float a = b1[j];
    #pragma unroll
    for (int c = 0; c < 32; ++c) a = fmaf(e[c], w1[c*64 + j], a);
    logit = fmaf(fmaxf(a, 0.f), w2[j], logit);
  }
  out_log[nid] = logit;
}

extern "C" void kernel_launch(void* const* d_in, const int* in_sizes, int n_in,
                              void* d_out, int out_size, void* d_ws, size_t ws_size,
                              hipStream_t stream) {
  const float* x    = (const float*)d_in[0];
  const int*   ei   = (const int*)  d_in[1];
  const float* s1wl = (const float*)d_in[2];
  const float* s1bl = (const float*)d_in[3];
  const float* s1wr = (const float*)d_in[4];
  const float* bn1g = (const float*)d_in[5];
  const float* bn1b = (const float*)d_in[6];
  const float* bn1m = (const float*)d_in[7];
  const float* bn1v = (const float*)d_in[8];
  const float* s2wl = (const float*)d_in[9];
  const float* s2bl = (const float*)d_in[10];
  const float* s2wr = (const float*)d_in[11];
  const float* bn2g = (const float*)d_in[12];
  const float* bn2b = (const float*)d_in[13];
  const float* bn2m = (const float*)d_in[14];
  const float* bn2v = (const float*)d_in[15];
  const float* gatw = (const float*)d_in[16];
  const float* atts = (const float*)d_in[17];
  const float* attd = (const float*)d_in[18];
  const float* gatb = (const float*)d_in[19];
  const float* cw1  = (const float*)d_in[20];
  const float* cb1  = (const float*)d_in[21];
  const float* cw2  = (const float*)d_in[22];
  const float* cb2  = (const float*)d_in[23];

  const int N = in_sizes[0] / 64;
  const int E = in_sizes[1] / 2;
  const int* src = ei;
  const int* dst = ei + E;

  // workspace layout (lifetime-aliased): ~81 MB
  float* A    = (float*)d_ws;            // [N*128] mean1 -> mean2 -> hg
  float* B    = A + (size_t)N*128;       // [N*128] h1
  float* C    = B + (size_t)N*128;       // [N*128] h2
  float* asrc = C + (size_t)N*128;       // [N*4]
  float* adst = asrc + (size_t)N*4;      // [N*4]
  float* mmax = adst + (size_t)N*4;      // [N*4]
  float* bnp  = mmax + (size_t)N*4;      // [512]
  int* degi = (int*)(bnp + 512);         // [N]
  int* offs = degi + N;                  // [N+1]
  int* cur  = offs + N + 1;              // [N]
  int* esrc = cur + N;                   // [E]

  float* out_emb = (float*)d_out;
  float* out_log = out_emb + (size_t)N*32;

  hipMemsetAsync(degi, 0, (size_t)N*4, stream);
  hipMemsetAsync(cur,  0, (size_t)N*4, stream);

  k_bnfold<<<1, 256, 0, stream>>>(bn1g,bn1b,bn1m,bn1v, bn2g,bn2b,bn2m,bn2v, bnp);

  // CSR build (shared by all 3 aggregations)
  k_deg<<<(E+TPB-1)/TPB, TPB, 0, stream>>>(dst, degi, E);
  k_scan<<<1, 1024, 0, stream>>>(degi, offs, N);
  k_fill<<<(E+TPB-1)/TPB, TPB, 0, stream>>>(src, dst, offs, cur, esrc, E);

  int nmb = (N + 15) / 16;

  // SAGE1: mean1 = gather(x); h1 = relu(bn(mean1@wl + bl + x@wr))
  k_gather_mean<64><<<(N+3)/4, 256, 0, stream>>>(offs, esrc, x, A, N);
  k_node_mm<64,true,true,false,true><<<nmb, 256, 0, stream>>>(
      x, A, s1wl, s1wr, s1bl, bnp, 0, nullptr, B, N);

  // SAGE2: mean2 = gather(h1); h2 = relu(bn(mean2@wl + bl + h1@wr) + h1)
  k_gather_mean<128><<<(N+1)/2, 256, 0, stream>>>(offs, esrc, B, A, N);
  k_node_mm<128,true,true,true,true><<<nmb, 256, 0, stream>>>(
      B, A, s2wl, s2wr, s2bl, bnp, 256, B, C, N);

  // GAT: hg = h2 @ gat_w
  k_node_mm<128,false,false,false,false><<<nmb, 256, 0, stream>>>(
      C, nullptr, nullptr, gatw, nullptr, nullptr, 0, nullptr, A, N);

  k_attn<<<(N*4+TPB-1)/TPB, TPB, 0, stream>>>(A, atts, attd, asrc, adst, N);
  k_gat_max<<<(N*4+TPB-1)/TPB, TPB, 0, stream>>>(offs, esrc, asrc, adst, mmax, N);
  k_gat<<<(N+1)/2, 256, 0, stream>>>(offs, esrc, asrc, adst, mmax, A, gatb, out_emb, N);

  k_final<<<(N+TPB-1)/TPB, TPB, 0, stream>>>(out_emb, cw1, cb1, cw2, cb2, out_log, N);
}

// Round 3
// 532.283 us; speedup vs baseline: 7.2637x; 1.4724x over previous
//
#include <hip/hip_runtime.h>

typedef unsigned int uint_t;
typedef unsigned short ush;

constexpr int TPB = 256;

__device__ __forceinline__ float lrelu(float x){ return x > 0.f ? x : 0.2f*x; }
__device__ __forceinline__ ush f2b(float f){            // fp32 -> bf16 RNE
  uint_t u = __float_as_uint(f);
  return (ush)((u + 0x7fffu + ((u >> 16) & 1u)) >> 16);
}
__device__ __forceinline__ float b2f(ush s){ return __uint_as_float(((uint_t)s) << 16); }

// fold BN eval params into scale/shift: out = [sc1(128), sh1(128), sc2(128), sh2(128)]
__global__ void k_bnfold(const float* __restrict__ g1, const float* __restrict__ b1,
                         const float* __restrict__ m1, const float* __restrict__ v1,
                         const float* __restrict__ g2, const float* __restrict__ b2,
                         const float* __restrict__ m2, const float* __restrict__ v2,
                         float* __restrict__ out){
  int t = threadIdx.x;
  int o = t & 127;
  bool second = t >= 128;
  const float* g = second ? g2 : g1;  const float* b = second ? b2 : b1;
  const float* m = second ? m2 : m1;  const float* v = second ? v2 : v1;
  float sc = g[o] * rsqrtf(v[o] + 1e-5f);
  float sh = b[o] - m[o]*sc;
  int off = second ? 256 : 0;
  out[off + o] = sc;
  out[off + 128 + o] = sh;
}

// ---------------- CSR build ----------------
__global__ void k_deg(const int* __restrict__ dst, int* __restrict__ degi, int E){
  int t = blockIdx.x*TPB + threadIdx.x;
  if (t < E) atomicAdd(&degi[dst[t]], 1);
}

// per-block (1024) exclusive scan; bsum[bid] = block total
__global__ __launch_bounds__(1024) void k_scan1(const int* __restrict__ deg,
                                                int* __restrict__ out,
                                                int* __restrict__ bsum, int n){
  __shared__ int ws[16];
  int tid = threadIdx.x;
  int gid = blockIdx.x*1024 + tid;
  int v = (gid < n) ? deg[gid] : 0;
  int lane = tid & 63, wid = tid >> 6;
  int s = v;
  for (int off = 1; off < 64; off <<= 1){
    int t2 = __shfl_up(s, off);
    if (lane >= off) s += t2;
  }
  if (lane == 63) ws[wid] = s;
  __syncthreads();
  if (wid == 0){
    int w = (lane < 16) ? ws[lane] : 0;
    for (int off = 1; off < 16; off <<= 1){
      int t2 = __shfl_up(w, off);
      if (lane >= off) w += t2;
    }
    if (lane < 16) ws[lane] = w;
  }
  __syncthreads();
  int base = wid > 0 ? ws[wid-1] : 0;
  int incl = base + s;
  if (gid < n) out[gid] = incl - v;   // exclusive within block
  if (tid == 1023) bsum[blockIdx.x] = incl;
}

// single-wave scan of block sums (in-place exclusive), total -> bsum[nb]
__global__ void k_scan2(int* __restrict__ bsum, int nb){
  int lane = threadIdx.x;  // 64
  int carry = 0;
  for (int base = 0; base < nb; base += 64){
    int i = base + lane;
    int v = (i < nb) ? bsum[i] : 0;
    int s = v;
    for (int off = 1; off < 64; off <<= 1){
      int t2 = __shfl_up(s, off);
      if (lane >= off) s += t2;
    }
    if (i < nb) bsum[i] = carry + s - v;
    int tot = __shfl(s, 63);
    carry += tot;
  }
  if (lane == 0) bsum[nb] = carry;
}

__global__ void k_scan3(int* __restrict__ offs, const int* __restrict__ bsum, int n, int nb){
  int gid = blockIdx.x*TPB + threadIdx.x;
  if (gid < n) offs[gid] += bsum[gid >> 10];
  else if (gid == n) offs[n] = bsum[nb];
}

__global__ void k_fill(const int* __restrict__ src, const int* __restrict__ dst,
                       const int* __restrict__ offs, int* __restrict__ cur,
                       int* __restrict__ esrc, int E){
  int t = blockIdx.x*TPB + threadIdx.x;
  if (t >= E) return;
  int d = dst[t];
  int p = offs[d] + atomicAdd(&cur[d], 1);
  esrc[p] = src[t];
}

// ---------------- fp32 -> bf16 conversion (x only; h1/hg fused into matmul epilogue) ----------------
__global__ void k_tobf16(const float* __restrict__ in, ush* __restrict__ out, int n4){
  int t = blockIdx.x*TPB + threadIdx.x;
  if (t >= n4) return;
  float4 v = *(const float4*)(in + (size_t)t*4);
  ushort4 o;
  o.x = f2b(v.x); o.y = f2b(v.y); o.z = f2b(v.z); o.w = f2b(v.w);
  *(ushort4*)(out + (size_t)t*4) = o;
}

// ---------------- mean aggregation via bf16 gather ----------------
// L = C/2 lanes per node; lane owns channel pair (2l, 2l+1) via one uint load.
template<int C>
__global__ __launch_bounds__(256) void k_gather_mean_b(
    const int* __restrict__ offs, const int* __restrict__ esrc,
    const uint_t* __restrict__ xb, float* __restrict__ mean, int n){
  constexpr int L = C/2;
  int tid = threadIdx.x;
  int nid = blockIdx.x*(256/L) + tid/L;
  int l = tid % L;
  if (nid >= n) return;
  int k0 = offs[nid], k1 = offs[nid+1];
  float s0 = 0.f, s1 = 0.f;
  for (int k = k0; k < k1; ++k){
    uint_t u = xb[(size_t)esrc[k]*L + l];
    s0 += b2f((ush)(u & 0xffffu));
    s1 += b2f((ush)(u >> 16));
  }
  float inv = 1.f / (float)max(k1 - k0, 1);
  *(float2*)(mean + (size_t)nid*C + 2*l) = make_float2(s0*inv, s1*inv);
}

// ---------------- node matmul: out = mean@wl + bias + x@wr, epilogue fused ----------------
template<int CIN, bool HAS_MEAN, bool BN, bool RES, bool RELU>
__global__ __launch_bounds__(256) void k_node_mm(
    const float* __restrict__ xr, const float* __restrict__ mean,
    const float* __restrict__ wl, const float* __restrict__ wr,
    const float* __restrict__ bias,
    const float* __restrict__ bnp, int bnoff,
    const float* __restrict__ res,
    float* __restrict__ out, ush* __restrict__ outb, int n)
{
  constexpr int NB = 16;
  constexpr int CO = 128;
  constexpr int CP = CIN + 4;
  constexpr int KCH = 32;
  __shared__ float sWr[KCH][CO];
  __shared__ float sWl[HAS_MEAN ? KCH : 1][HAS_MEAN ? CO : 1];
  __shared__ float sX[NB][CP];
  __shared__ float sM[HAS_MEAN ? NB : 1][HAS_MEAN ? CP : 1];
  int tid = threadIdx.x;
  int node0 = blockIdx.x * NB;
  int nl = tid >> 4;
  int o4 = (tid & 15) * 4;

  for (int idx = tid; idx < NB*CIN/4; idx += 256) {
    int p = idx * 4;
    int node = p / CIN, c = p % CIN;
    int g = node0 + node;
    float4 xv = make_float4(0.f,0.f,0.f,0.f);
    float4 mv = make_float4(0.f,0.f,0.f,0.f);
    if (g < n){
      xv = *(const float4*)(xr + (size_t)g*CIN + c);
      if constexpr (HAS_MEAN) mv = *(const float4*)(mean + (size_t)g*CIN + c);
    }
    *(float4*)&sX[node][c] = xv;
    if constexpr (HAS_MEAN) *(float4*)&sM[node][c] = mv;
  }

  float accA[4] = {0,0,0,0};
  float accB[4] = {0,0,0,0};

  for (int kc = 0; kc < CIN; kc += KCH) {
    __syncthreads();
    for (int idx = tid; idx < KCH*CO/4; idx += 256) {
      int p = idx * 4;
      int k = p / CO, oo = p % CO;
      *(float4*)&sWr[k][oo] = *(const float4*)(wr + (size_t)(kc+k)*CO + oo);
      if constexpr (HAS_MEAN)
        *(float4*)&sWl[k][oo] = *(const float4*)(wl + (size_t)(kc+k)*CO + oo);
    }
    __syncthreads();
    #pragma unroll
    for (int k = 0; k < KCH; ++k) {
      float xv = sX[nl][kc + k];
      float4 wra = *(const float4*)&sWr[k][o4];
      float4 wrb = *(const float4*)&sWr[k][o4 + 64];
      accA[0] = fmaf(xv, wra.x, accA[0]);
      accA[1] = fmaf(xv, wra.y, accA[1]);
      accA[2] = fmaf(xv, wra.z, accA[2]);
      accA[3] = fmaf(xv, wra.w, accA[3]);
      accB[0] = fmaf(xv, wrb.x, accB[0]);
      accB[1] = fmaf(xv, wrb.y, accB[1]);
      accB[2] = fmaf(xv, wrb.z, accB[2]);
      accB[3] = fmaf(xv, wrb.w, accB[3]);
      if constexpr (HAS_MEAN) {
        float mv = sM[nl][kc + k];
        float4 wla = *(const float4*)&sWl[k][o4];
        float4 wlb = *(const float4*)&sWl[k][o4 + 64];
        accA[0] = fmaf(mv, wla.x, accA[0]);
        accA[1] = fmaf(mv, wla.y, accA[1]);
        accA[2] = fmaf(mv, wla.z, accA[2]);
        accA[3] = fmaf(mv, wla.w, accA[3]);
        accB[0] = fmaf(mv, wlb.x, accB[0]);
        accB[1] = fmaf(mv, wlb.y, accB[1]);
        accB[2] = fmaf(mv, wlb.z, accB[2]);
        accB[3] = fmaf(mv, wlb.w, accB[3]);
      }
    }
  }

  int g = node0 + nl;
  if (g < n) {
    float* accs[2] = {accA, accB};
    #pragma unroll
    for (int q = 0; q < 2; ++q) {
      int o = o4 + q*64;
      float* a = accs[q];
      float vv[4];
      #pragma unroll
      for (int j = 0; j < 4; ++j) {
        float t = a[j];
        if (bias) t += bias[o + j];
        if constexpr (BN) t = t * bnp[bnoff + o + j] + bnp[bnoff + 128 + o + j];
        vv[j] = t;
      }
      if constexpr (RES) {
        float4 rv = *(const float4*)(res + (size_t)g*CO + o);
        vv[0] += rv.x; vv[1] += rv.y; vv[2] += rv.z; vv[3] += rv.w;
      }
      if constexpr (RELU) {
        vv[0] = fmaxf(vv[0], 0.f); vv[1] = fmaxf(vv[1], 0.f);
        vv[2] = fmaxf(vv[2], 0.f); vv[3] = fmaxf(vv[3], 0.f);
      }
      if (out)
        *(float4*)(out + (size_t)g*CO + o) = make_float4(vv[0], vv[1], vv[2], vv[3]);
      if (outb){
        ushort4 pb;
        pb.x = f2b(vv[0]); pb.y = f2b(vv[1]); pb.z = f2b(vv[2]); pb.w = f2b(vv[3]);
        *(ushort4*)(outb + (size_t)g*CO + o) = pb;
      }
    }
  }
}

// ---------------- GAT ----------------
// attention scalars from bf16 hg
__global__ void k_attn(const uint_t* __restrict__ hgb, const float* __restrict__ atts,
                       const float* __restrict__ attd, float* __restrict__ asrc,
                       float* __restrict__ adst, int n){
  int t = blockIdx.x*TPB + threadIdx.x;
  if (t >= n*4) return;
  int nid = t >> 2, h = t & 3;
  const uint_t* hp = hgb + (size_t)nid*64 + h*16;
  float as = 0.f, ad = 0.f;
  #pragma unroll
  for (int i = 0; i < 16; ++i) {
    uint_t u = hp[i];
    float v0 = b2f((ush)(u & 0xffffu));
    float v1 = b2f((ush)(u >> 16));
    as = fmaf(v0, atts[h*32 + 2*i],     as);
    as = fmaf(v1, atts[h*32 + 2*i + 1], as);
    ad = fmaf(v0, attd[h*32 + 2*i],     ad);
    ad = fmaf(v1, attd[h*32 + 2*i + 1], ad);
  }
  asrc[t] = as; adst[t] = ad;
}

// fused softmax gather (no max shift: logits are O(8), exp exact & safe) + head-mean + bias
__global__ __launch_bounds__(256) void k_gat(
    const int* __restrict__ offs, const int* __restrict__ esrc,
    const float* __restrict__ asrc, const float* __restrict__ adst,
    const uint_t* __restrict__ hgb, const float* __restrict__ gbias,
    float* __restrict__ out_emb, int n){
  int tid = threadIdx.x;
  int l = tid & 63;                   // one wave per node; lane owns channels 2l, 2l+1
  int nid = blockIdx.x*4 + (tid >> 6);
  if (nid >= n) return;
  int h = l >> 4;
  int i4 = nid*4 + h;
  float ad = adst[i4];
  float e0 = expf(lrelu(asrc[i4] + ad));                 // self-loop
  uint_t u = hgb[(size_t)nid*64 + l];
  float accD  = e0;
  float accN0 = e0 * b2f((ush)(u & 0xffffu));
  float accN1 = e0 * b2f((ush)(u >> 16));
  int k0 = offs[nid], k1 = offs[nid+1];
  for (int k = k0; k < k1; ++k){
    int s = esrc[k];
    float e = expf(lrelu(asrc[s*4 + h] + ad));
    uint_t v = hgb[(size_t)s*64 + l];
    accD += e;
    accN0 = fmaf(e, b2f((ush)(v & 0xffffu)), accN0);
    accN1 = fmaf(e, b2f((ush)(v >> 16)),     accN1);
  }
  float inv = 1.f / accD;
  float v0 = accN0 * inv, v1 = accN1 * inv;
  // head-mean: lanes {l, l^16, l^32, l^48} hold the 4 heads of channel pair (2l&31)
  v0 += __shfl_xor(v0, 16); v0 += __shfl_xor(v0, 32);
  v1 += __shfl_xor(v1, 16); v1 += __shfl_xor(v1, 32);
  if (l < 16){
    int c = l*2;
    float2 o;
    o.x = 0.25f*v0 + gbias[c];
    o.y = 0.25f*v1 + gbias[c+1];
    *(float2*)(out_emb + (size_t)nid*32 + c) = o;
  }
}

// classifier MLP
__global__ void k_final(const float* __restrict__ emb,
                        const float* __restrict__ w1, const float* __restrict__ b1,
                        const float* __restrict__ w2, const float* __restrict__ b2,
                        float* __restrict__ out_log, int n){
  int nid = blockIdx.x*TPB + threadIdx.x;
  if (nid >= n) return;
  float e[32];
  #pragma unroll
  for (int c = 0; c < 32; ++c) e[c] = emb[(size_t)nid*32 + c];
  float logit = b2[0];
  for (int j = 0; j < 64; ++j) {
    float a = b1[j];
    #pragma unroll
    for (int c = 0; c < 32; ++c) a = fmaf(e[c], w1[c*64 + j], a);
    logit = fmaf(fmaxf(a, 0.f), w2[j], logit);
  }
  out_log[nid] = logit;
}

extern "C" void kernel_launch(void* const* d_in, const int* in_sizes, int n_in,
                              void* d_out, int out_size, void* d_ws, size_t ws_size,
                              hipStream_t stream) {
  const float* x    = (const float*)d_in[0];
  const int*   ei   = (const int*)  d_in[1];
  const float* s1wl = (const float*)d_in[2];
  const float* s1bl = (const float*)d_in[3];
  const float* s1wr = (const float*)d_in[4];
  const float* bn1g = (const float*)d_in[5];
  const float* bn1b = (const float*)d_in[6];
  const float* bn1m = (const float*)d_in[7];
  const float* bn1v = (const float*)d_in[8];
  const float* s2wl = (const float*)d_in[9];
  const float* s2bl = (const float*)d_in[10];
  const float* s2wr = (const float*)d_in[11];
  const float* bn2g = (const float*)d_in[12];
  const float* bn2b = (const float*)d_in[13];
  const float* bn2m = (const float*)d_in[14];
  const float* bn2v = (const float*)d_in[15];
  const float* gatw = (const float*)d_in[16];
  const float* atts = (const float*)d_in[17];
  const float* attd = (const float*)d_in[18];
  const float* gatb = (const float*)d_in[19];
  const float* cw1  = (const float*)d_in[20];
  const float* cb1  = (const float*)d_in[21];
  const float* cw2  = (const float*)d_in[22];
  const float* cb2  = (const float*)d_in[23];

  const int N = in_sizes[0] / 64;
  const int E = in_sizes[1] / 2;
  const int* src = ei;
  const int* dst = ei + E;
  const int NBK = (N + 1023) / 1024;

  // workspace (lifetime-aliased):
  float* A    = (float*)d_ws;            // [N*128] mean1 -> mean2 -> hgb(bf16, first half)
  float* B    = A + (size_t)N*128;       // [N*128] h1 fp32
  float* C    = B + (size_t)N*128;       // [N*128] xb(bf16) -> h1b(bf16) -> h2 fp32
  float* asrc = C + (size_t)N*128;       // [N*4]
  float* adst = asrc + (size_t)N*4;      // [N*4]
  float* bnp  = adst + (size_t)N*4;      // [512]
  int* degi = (int*)(bnp + 512);         // [N]
  int* offs = degi + N;                  // [N+1]
  int* cur  = offs + N + 1;              // [N]
  int* esrc = cur + N;                   // [E]
  int* bsum = esrc + E;                  // [NBK+1]
  ush* xb  = (ush*)C;                    // [N*64]  bf16 x
  ush* h1b = (ush*)C;                    // [N*128] bf16 h1 (after xb dead)
  ush* hgb = (ush*)A;                    // [N*128] bf16 hg (after mean2 dead)

  float* out_emb = (float*)d_out;
  float* out_log = out_emb + (size_t)N*32;

  hipMemsetAsync(degi, 0, (size_t)N*4, stream);
  hipMemsetAsync(cur,  0, (size_t)N*4, stream);

  k_bnfold<<<1, 256, 0, stream>>>(bn1g,bn1b,bn1m,bn1v, bn2g,bn2b,bn2m,bn2v, bnp);

  // CSR build (shared by all 3 aggregations)
  k_deg<<<(E+TPB-1)/TPB, TPB, 0, stream>>>(dst, degi, E);
  k_scan1<<<NBK, 1024, 0, stream>>>(degi, offs, bsum, N);
  k_scan2<<<1, 64, 0, stream>>>(bsum, NBK);
  k_scan3<<<(N+1+TPB-1)/TPB, TPB, 0, stream>>>(offs, bsum, N, NBK);
  k_fill<<<(E+TPB-1)/TPB, TPB, 0, stream>>>(src, dst, offs, cur, esrc, E);

  k_tobf16<<<(N*16+TPB-1)/TPB, TPB, 0, stream>>>(x, xb, N*16);

  int nmb = (N + 15) / 16;

  // SAGE1: mean1 = gather(xb); h1 = relu(bn(mean1@wl + bl + x@wr))  [+ h1b bf16]
  k_gather_mean_b<64><<<(N+7)/8, 256, 0, stream>>>(offs, esrc, (const uint_t*)xb, A, N);
  k_node_mm<64,true,true,false,true><<<nmb, 256, 0, stream>>>(
      x, A, s1wl, s1wr, s1bl, bnp, 0, nullptr, B, h1b, N);

  // SAGE2: mean2 = gather(h1b); h2 = relu(bn(mean2@wl + bl + h1@wr) + h1)
  k_gather_mean_b<128><<<(N+3)/4, 256, 0, stream>>>(offs, esrc, (const uint_t*)h1b, A, N);
  k_node_mm<128,true,true,true,true><<<nmb, 256, 0, stream>>>(
      B, A, s2wl, s2wr, s2bl, bnp, 256, B, C, nullptr, N);

  // GAT: hgb = bf16(h2 @ gat_w)
  k_node_mm<128,false,false,false,false><<<nmb, 256, 0, stream>>>(
      C, nullptr, nullptr, gatw, nullptr, nullptr, 0, nullptr, nullptr, hgb, N);

  k_attn<<<(N*4+TPB-1)/TPB, TPB, 0, stream>>>((const uint_t*)hgb, atts, attd, asrc, adst, N);
  k_gat<<<(N+3)/4, 256, 0, stream>>>(offs, esrc, asrc, adst, (const uint_t*)hgb, gatb, out_emb, N);

  k_final<<<(N+TPB-1)/TPB, TPB, 0, stream>>>(out_emb, cw1, cb1, cw2, cb2, out_log, N);
}

// Round 4
// 405.444 us; speedup vs baseline: 9.5361x; 1.3128x over previous
//
#include <hip/hip_runtime.h>

typedef unsigned int uint_t;
typedef unsigned short ush;
typedef short bf16x8 __attribute__((ext_vector_type(8)));
typedef float f32x4 __attribute__((ext_vector_type(4)));

constexpr int TPB = 256;

__device__ __forceinline__ float lrelu(float x){ return x > 0.f ? x : 0.2f*x; }
__device__ __forceinline__ ush f2b(float f){            // fp32 -> bf16 RNE
  uint_t u = __float_as_uint(f);
  return (ush)((u + 0x7fffu + ((u >> 16) & 1u)) >> 16);
}
__device__ __forceinline__ float b2f(ush s){ return __uint_as_float(((uint_t)s) << 16); }

// fold BN eval params into scale/shift: out = [sc1(128), sh1(128), sc2(128), sh2(128)]
__global__ void k_bnfold(const float* __restrict__ g1, const float* __restrict__ b1,
                         const float* __restrict__ m1, const float* __restrict__ v1,
                         const float* __restrict__ g2, const float* __restrict__ b2,
                         const float* __restrict__ m2, const float* __restrict__ v2,
                         float* __restrict__ out){
  int t = threadIdx.x;
  int o = t & 127;
  bool second = t >= 128;
  const float* g = second ? g2 : g1;  const float* b = second ? b2 : b1;
  const float* m = second ? m2 : m1;  const float* v = second ? v2 : v1;
  float sc = g[o] * rsqrtf(v[o] + 1e-5f);
  float sh = b[o] - m[o]*sc;
  int off = second ? 256 : 0;
  out[off + o] = sc;
  out[off + 128 + o] = sh;
}

// ---------------- CSR build ----------------
__global__ void k_deg(const int* __restrict__ dst, int* __restrict__ degi, int E){
  int t = blockIdx.x*TPB + threadIdx.x;
  if (t < E) atomicAdd(&degi[dst[t]], 1);
}

__global__ __launch_bounds__(1024) void k_scan1(const int* __restrict__ deg,
                                                int* __restrict__ out,
                                                int* __restrict__ bsum, int n){
  __shared__ int ws[16];
  int tid = threadIdx.x;
  int gid = blockIdx.x*1024 + tid;
  int v = (gid < n) ? deg[gid] : 0;
  int lane = tid & 63, wid = tid >> 6;
  int s = v;
  for (int off = 1; off < 64; off <<= 1){
    int t2 = __shfl_up(s, off);
    if (lane >= off) s += t2;
  }
  if (lane == 63) ws[wid] = s;
  __syncthreads();
  if (wid == 0){
    int w = (lane < 16) ? ws[lane] : 0;
    for (int off = 1; off < 16; off <<= 1){
      int t2 = __shfl_up(w, off);
      if (lane >= off) w += t2;
    }
    if (lane < 16) ws[lane] = w;
  }
  __syncthreads();
  int base = wid > 0 ? ws[wid-1] : 0;
  int incl = base + s;
  if (gid < n) out[gid] = incl - v;
  if (tid == 1023) bsum[blockIdx.x] = incl;
}

__global__ void k_scan2(int* __restrict__ bsum, int nb){
  int lane = threadIdx.x;  // 64
  int carry = 0;
  for (int base = 0; base < nb; base += 64){
    int i = base + lane;
    int v = (i < nb) ? bsum[i] : 0;
    int s = v;
    for (int off = 1; off < 64; off <<= 1){
      int t2 = __shfl_up(s, off);
      if (lane >= off) s += t2;
    }
    if (i < nb) bsum[i] = carry + s - v;
    int tot = __shfl(s, 63);
    carry += tot;
  }
  if (lane == 0) bsum[nb] = carry;
}

__global__ void k_scan3(int* __restrict__ offs, const int* __restrict__ bsum, int n, int nb){
  int gid = blockIdx.x*TPB + threadIdx.x;
  if (gid < n) offs[gid] += bsum[gid >> 10];
  else if (gid == n) offs[n] = bsum[nb];
}

__global__ void k_fill(const int* __restrict__ src, const int* __restrict__ dst,
                       const int* __restrict__ offs, int* __restrict__ cur,
                       int* __restrict__ esrc, int E){
  int t = blockIdx.x*TPB + threadIdx.x;
  if (t >= E) return;
  int d = dst[t];
  int p = offs[d] + atomicAdd(&cur[d], 1);
  esrc[p] = src[t];
}

// ---------------- fp32 -> bf16 ----------------
__global__ void k_tobf16(const float* __restrict__ in, ush* __restrict__ out, int n4){
  int t = blockIdx.x*TPB + threadIdx.x;
  if (t >= n4) return;
  float4 v = *(const float4*)(in + (size_t)t*4);
  ushort4 o;
  o.x = f2b(v.x); o.y = f2b(v.y); o.z = f2b(v.z); o.w = f2b(v.w);
  *(ushort4*)(out + (size_t)t*4) = o;
}

// weight prep: WT[n][k] = bf16( k<C1 ? wr[k][n] : wl[k-C1][n] ), n in [0,128)
__global__ void k_wprep(const float* __restrict__ wr, const float* __restrict__ wl,
                        int C1, int K, ush* __restrict__ WT){
  int t = blockIdx.x*TPB + threadIdx.x;
  if (t >= 128*K) return;
  int n = t / K, k = t % K;
  float v = (k < C1) ? wr[(size_t)k*128 + n] : wl[(size_t)(k - C1)*128 + n];
  WT[t] = f2b(v);
}

// ---------------- mean aggregation via bf16 gather -> bf16 mean ----------------
template<int C>
__global__ __launch_bounds__(256) void k_gather_mean_b(
    const int* __restrict__ offs, const int* __restrict__ esrc,
    const uint_t* __restrict__ xb, uint_t* __restrict__ meanb, int n){
  constexpr int L = C/2;
  int tid = threadIdx.x;
  int nid = blockIdx.x*(256/L) + tid/L;
  int l = tid % L;
  if (nid >= n) return;
  int k0 = offs[nid], k1 = offs[nid+1];
  float s0 = 0.f, s1 = 0.f;
  for (int k = k0; k < k1; ++k){
    uint_t u = xb[(size_t)esrc[k]*L + l];
    s0 += b2f((ush)(u & 0xffffu));
    s1 += b2f((ush)(u >> 16));
  }
  float inv = 1.f / (float)max(k1 - k0, 1);
  uint_t lo = f2b(s0*inv), hi = f2b(s1*inv);
  meanb[(size_t)nid*L + l] = lo | (hi << 16);
}

// ---------------- MFMA node matmul: out = [A1|A2] @ W, fused epilogue ----------------
// 32 nodes/block, 256 threads = 4 waves; wave w owns output cols [32w, 32w+32).
template<int K, bool BN, bool RES, bool RELU>
__global__ __launch_bounds__(256) void k_mm_mfma(
    const ush* __restrict__ A1, int C1,
    const ush* __restrict__ A2,
    const ush* __restrict__ WT,            // [128][K] bf16
    const float* __restrict__ bias,
    const float* __restrict__ bnp, int bnoff,
    const float* __restrict__ res,
    float* __restrict__ out, ush* __restrict__ outb, int n)
{
  constexpr int PAD = K + 8;               // 2-way (free) LDS pattern on ds_read_b128
  __shared__ ush sA[32][PAD];
  int tid = threadIdx.x;
  int wave = tid >> 6, lane = tid & 63;
  int node0 = blockIdx.x * 32;
  int C2 = K - C1;

  for (int idx = tid; idx < 32*(K/8); idx += 256) {
    int r  = idx / (K/8);
    int kc = (idx % (K/8)) * 8;
    int g = node0 + r;
    uint4 v = make_uint4(0,0,0,0);
    if (g < n) {
      if (kc < C1) v = *(const uint4*)(A1 + (size_t)g*C1 + kc);
      else         v = *(const uint4*)(A2 + (size_t)g*C2 + (kc - C1));
    }
    *(uint4*)&sA[r][kc] = v;
  }
  __syncthreads();

  f32x4 acc[2][2] = {};
  int l15 = lane & 15, lk = (lane >> 4) * 8;
  const ush* wt0 = WT + (size_t)(wave*32 + l15) * K + lk;
  const ush* wt1 = wt0 + (size_t)16 * K;

  #pragma unroll
  for (int kk = 0; kk < K; kk += 32) {
    bf16x8 a0 = *(const bf16x8*)&sA[l15][kk + lk];
    bf16x8 a1 = *(const bf16x8*)&sA[16 + l15][kk + lk];
    bf16x8 b0 = *(const bf16x8*)(wt0 + kk);
    bf16x8 b1 = *(const bf16x8*)(wt1 + kk);
    acc[0][0] = __builtin_amdgcn_mfma_f32_16x16x32_bf16(a0, b0, acc[0][0], 0, 0, 0);
    acc[0][1] = __builtin_amdgcn_mfma_f32_16x16x32_bf16(a0, b1, acc[0][1], 0, 0, 0);
    acc[1][0] = __builtin_amdgcn_mfma_f32_16x16x32_bf16(a1, b0, acc[1][0], 0, 0, 0);
    acc[1][1] = __builtin_amdgcn_mfma_f32_16x16x32_bf16(a1, b1, acc[1][1], 0, 0, 0);
  }

  // D layout: col = lane&15, row = (lane>>4)*4 + j  [m89-verified]
  int r0 = (lane >> 4) * 4;
  #pragma unroll
  for (int mt = 0; mt < 2; ++mt) {
    #pragma unroll
    for (int nt = 0; nt < 2; ++nt) {
      int nn = wave*32 + nt*16 + l15;
      float bv = bias ? bias[nn] : 0.f;
      float sc = 1.f, sh = 0.f;
      if constexpr (BN) { sc = bnp[bnoff + nn]; sh = bnp[bnoff + 128 + nn]; }
      #pragma unroll
      for (int j = 0; j < 4; ++j) {
        int g = node0 + mt*16 + r0 + j;
        if (g < n) {
          float v = acc[mt][nt][j] + bv;
          if constexpr (BN)   v = v*sc + sh;
          if constexpr (RES)  v += res[(size_t)g*128 + nn];
          if constexpr (RELU) v = fmaxf(v, 0.f);
          if (out)  out[(size_t)g*128 + nn] = v;
          if (outb) outb[(size_t)g*128 + nn] = f2b(v);
        }
      }
    }
  }
}

// ---------------- GAT ----------------
__global__ void k_attn(const uint_t* __restrict__ hgb, const float* __restrict__ atts,
                       const float* __restrict__ attd, float* __restrict__ asrc,
                       float* __restrict__ adst, int n){
  int t = blockIdx.x*TPB + threadIdx.x;
  if (t >= n*4) return;
  int nid = t >> 2, h = t & 3;
  const uint_t* hp = hgb + (size_t)nid*64 + h*16;
  float as = 0.f, ad = 0.f;
  #pragma unroll
  for (int i = 0; i < 16; ++i) {
    uint_t u = hp[i];
    float v0 = b2f((ush)(u & 0xffffu));
    float v1 = b2f((ush)(u >> 16));
    as = fmaf(v0, atts[h*32 + 2*i],     as);
    as = fmaf(v1, atts[h*32 + 2*i + 1], as);
    ad = fmaf(v0, attd[h*32 + 2*i],     ad);
    ad = fmaf(v1, attd[h*32 + 2*i + 1], ad);
  }
  asrc[t] = as; adst[t] = ad;
}

// fused softmax gather (logits O(1) -> exp without max shift is exact) + head-mean + bias
__global__ __launch_bounds__(256) void k_gat(
    const int* __restrict__ offs, const int* __restrict__ esrc,
    const float* __restrict__ asrc, const float* __restrict__ adst,
    const uint_t* __restrict__ hgb, const float* __restrict__ gbias,
    float* __restrict__ out_emb, int n){
  int tid = threadIdx.x;
  int l = tid & 63;
  int nid = blockIdx.x*4 + (tid >> 6);
  if (nid >= n) return;
  int h = l >> 4;
  int i4 = nid*4 + h;
  float ad = adst[i4];
  float e0 = expf(lrelu(asrc[i4] + ad));                 // self-loop
  uint_t u = hgb[(size_t)nid*64 + l];
  float accD  = e0;
  float accN0 = e0 * b2f((ush)(u & 0xffffu));
  float accN1 = e0 * b2f((ush)(u >> 16));
  int k0 = offs[nid], k1 = offs[nid+1];
  for (int k = k0; k < k1; ++k){
    int s = esrc[k];
    float e = expf(lrelu(asrc[s*4 + h] + ad));
    uint_t v = hgb[(size_t)s*64 + l];
    accD += e;
    accN0 = fmaf(e, b2f((ush)(v & 0xffffu)), accN0);
    accN1 = fmaf(e, b2f((ush)(v >> 16)),     accN1);
  }
  float inv = 1.f / accD;
  float v0 = accN0 * inv, v1 = accN1 * inv;
  v0 += __shfl_xor(v0, 16); v0 += __shfl_xor(v0, 32);
  v1 += __shfl_xor(v1, 16); v1 += __shfl_xor(v1, 32);
  if (l < 16){
    int c = l*2;
    float2 o;
    o.x = 0.25f*v0 + gbias[c];
    o.y = 0.25f*v1 + gbias[c+1];
    *(float2*)(out_emb + (size_t)nid*32 + c) = o;
  }
}

// classifier MLP
__global__ void k_final(const float* __restrict__ emb,
                        const float* __restrict__ w1, const float* __restrict__ b1,
                        const float* __restrict__ w2, const float* __restrict__ b2,
                        float* __restrict__ out_log, int n){
  int nid = blockIdx.x*TPB + threadIdx.x;
  if (nid >= n) return;
  float e[32];
  #pragma unroll
  for (int c = 0; c < 32; ++c) e[c] = emb[(size_t)nid*32 + c];
  float logit = b2[0];
  for (int j = 0; j < 64; ++j) {
    float a = b1[j];
    #pragma unroll
    for (int c = 0; c < 32; ++c) a = fmaf(e[c], w1[c*64 + j], a);
    logit = fmaf(fmaxf(a, 0.f), w2[j], logit);
  }
  out_log[nid] = logit;
}

extern "C" void kernel_launch(void* const* d_in, const int* in_sizes, int n_in,
                              void* d_out, int out_size, void* d_ws, size_t ws_size,
                              hipStream_t stream) {
  const float* x    = (const float*)d_in[0];
  const int*   ei   = (const int*)  d_in[1];
  const float* s1wl = (const float*)d_in[2];
  const float* s1bl = (const float*)d_in[3];
  const float* s1wr = (const float*)d_in[4];
  const float* bn1g = (const float*)d_in[5];
  const float* bn1b = (const float*)d_in[6];
  const float* bn1m = (const float*)d_in[7];
  const float* bn1v = (const float*)d_in[8];
  const float* s2wl = (const float*)d_in[9];
  const float* s2bl = (const float*)d_in[10];
  const float* s2wr = (const float*)d_in[11];
  const float* bn2g = (const float*)d_in[12];
  const float* bn2b = (const float*)d_in[13];
  const float* bn2m = (const float*)d_in[14];
  const float* bn2v = (const float*)d_in[15];
  const float* gatw = (const float*)d_in[16];
  const float* atts = (const float*)d_in[17];
  const float* attd = (const float*)d_in[18];
  const float* gatb = (const float*)d_in[19];
  const float* cw1  = (const float*)d_in[20];
  const float* cb1  = (const float*)d_in[21];
  const float* cw2  = (const float*)d_in[22];
  const float* cb2  = (const float*)d_in[23];

  const int N = in_sizes[0] / 64;
  const int E = in_sizes[1] / 2;
  const int* src = ei;
  const int* dst = ei + E;
  const int NBK = (N + 1023) / 1024;

  // ---- workspace layout (lifetime-aliased, ~69 MB) ----
  float* h1   = (float*)d_ws;            // [N*128] fp32 (residual)
  float* asrc = h1 + (size_t)N*128;      // [N*4]
  float* adst = asrc + (size_t)N*4;      // [N*4]
  float* bnp  = adst + (size_t)N*4;      // [512]
  ush* regA = (ush*)(bnp + 512);         // [N*128] : xb(N*64) + mean1b(N*64) -> mean2b(N*128)
  ush* regB = regA + (size_t)N*128;      // [N*128] : h1b -> hgb
  ush* regC = regB + (size_t)N*128;      // [N*128] : h2b
  ush* W1T  = regC + (size_t)N*128;      // [128*128]
  ush* W2T  = W1T + 128*128;             // [128*256]
  ush* WGT  = W2T + 128*256;             // [128*128]
  int* degi = (int*)(WGT + 128*128);     // [N]
  int* offs = degi + N;                  // [N+1]
  int* cur  = offs + N + 1;              // [N]
  int* esrc = cur + N;                   // [E]
  int* bsum = esrc + E;                  // [NBK+1]

  ush* xb     = regA;                    // [N*64]
  ush* mean1b = regA + (size_t)N*64;     // [N*64]
  ush* mean2b = regA;                    // [N*128] (xb/mean1b dead)
  ush* h1b    = regB;                    // [N*128]
  ush* hgb    = regB;                    // [N*128] (h1b dead after SAGE2 mm)
  ush* h2b    = regC;                    // [N*128]

  float* out_emb = (float*)d_out;
  float* out_log = out_emb + (size_t)N*32;

  hipMemsetAsync(degi, 0, (size_t)N*4, stream);
  hipMemsetAsync(cur,  0, (size_t)N*4, stream);

  k_bnfold<<<1, 256, 0, stream>>>(bn1g,bn1b,bn1m,bn1v, bn2g,bn2b,bn2m,bn2v, bnp);

  // CSR build
  k_deg<<<(E+TPB-1)/TPB, TPB, 0, stream>>>(dst, degi, E);
  k_scan1<<<NBK, 1024, 0, stream>>>(degi, offs, bsum, N);
  k_scan2<<<1, 64, 0, stream>>>(bsum, NBK);
  k_scan3<<<(N+1+TPB-1)/TPB, TPB, 0, stream>>>(offs, bsum, N, NBK);
  k_fill<<<(E+TPB-1)/TPB, TPB, 0, stream>>>(src, dst, offs, cur, esrc, E);

  // weight prep (bf16, transposed+stacked)
  k_wprep<<<(128*128+TPB-1)/TPB, TPB, 0, stream>>>(s1wr, s1wl, 64, 128, W1T);
  k_wprep<<<(128*256+TPB-1)/TPB, TPB, 0, stream>>>(s2wr, s2wl, 128, 256, W2T);
  k_wprep<<<(128*128+TPB-1)/TPB, TPB, 0, stream>>>(gatw, nullptr, 128, 128, WGT);

  k_tobf16<<<(N*16+TPB-1)/TPB, TPB, 0, stream>>>(x, xb, N*16);

  int nmm = (N + 31) / 32;

  // SAGE1: mean1b = gather(xb); h1 = relu(bn([xb|mean1b]@W1 + b1)); h1b = bf16(h1)
  k_gather_mean_b<64><<<(N+7)/8, 256, 0, stream>>>(offs, esrc, (const uint_t*)xb, (uint_t*)mean1b, N);
  k_mm_mfma<128,true,false,true><<<nmm, 256, 0, stream>>>(
      xb, 64, mean1b, W1T, s1bl, bnp, 0, nullptr, h1, h1b, N);

  // SAGE2: mean2b = gather(h1b); h2b = bf16(relu(bn([h1b|mean2b]@W2 + b2) + h1))
  k_gather_mean_b<128><<<(N+3)/4, 256, 0, stream>>>(offs, esrc, (const uint_t*)h1b, (uint_t*)mean2b, N);
  k_mm_mfma<256,true,true,true><<<nmm, 256, 0, stream>>>(
      h1b, 128, mean2b, W2T, s2bl, bnp, 256, h1, nullptr, h2b, N);

  // GAT: hgb = bf16(h2b @ Wg)
  k_mm_mfma<128,false,false,false><<<nmm, 256, 0, stream>>>(
      h2b, 128, nullptr, WGT, nullptr, bnp, 0, nullptr, nullptr, hgb, N);

  k_attn<<<(N*4+TPB-1)/TPB, TPB, 0, stream>>>((const uint_t*)hgb, atts, attd, asrc, adst, N);
  k_gat<<<(N+3)/4, 256, 0, stream>>>(offs, esrc, asrc, adst, (const uint_t*)hgb, gatb, out_emb, N);

  k_final<<<(N+TPB-1)/TPB, TPB, 0, stream>>>(out_emb, cw1, cb1, cw2, cb2, out_log, N);
}

// Round 5
// 284.291 us; speedup vs baseline: 13.6000x; 1.4262x over previous
//
#include <hip/hip_runtime.h>

typedef unsigned int uint_t;
typedef unsigned short ush;
typedef short bf16x8 __attribute__((ext_vector_type(8)));
typedef float f32x4 __attribute__((ext_vector_type(4)));

constexpr int TPB = 256;
#define LOG2E 1.4426950408889634f

__device__ __forceinline__ float lrelu(float x){ return fmaxf(x, 0.f) + 0.2f*fminf(x, 0.f); }
__device__ __forceinline__ ush f2b(float f){            // fp32 -> bf16 RNE
  uint_t u = __float_as_uint(f);
  return (ush)((u + 0x7fffu + ((u >> 16) & 1u)) >> 16);
}
__device__ __forceinline__ float b2f(ush s){ return __uint_as_float(((uint_t)s) << 16); }
__device__ __forceinline__ float eexp(float x){ return exp2f(x * LOG2E); }

// fold BN eval params into scale/shift: out = [sc1(128), sh1(128), sc2(128), sh2(128)]
__global__ void k_bnfold(const float* __restrict__ g1, const float* __restrict__ b1,
                         const float* __restrict__ m1, const float* __restrict__ v1,
                         const float* __restrict__ g2, const float* __restrict__ b2,
                         const float* __restrict__ m2, const float* __restrict__ v2,
                         float* __restrict__ out){
  int t = threadIdx.x;
  int o = t & 127;
  bool second = t >= 128;
  const float* g = second ? g2 : g1;  const float* b = second ? b2 : b1;
  const float* m = second ? m2 : m1;  const float* v = second ? v2 : v1;
  float sc = g[o] * rsqrtf(v[o] + 1e-5f);
  float sh = b[o] - m[o]*sc;
  int off = second ? 256 : 0;
  out[off + o] = sc;
  out[off + 128 + o] = sh;
}

// ---------------- CSR build ----------------
__global__ void k_deg(const int* __restrict__ dst, int* __restrict__ degi, int E){
  int t = blockIdx.x*TPB + threadIdx.x;
  if (t < E) atomicAdd(&degi[dst[t]], 1);
}

__global__ __launch_bounds__(1024) void k_scan1(const int* __restrict__ deg,
                                                int* __restrict__ out,
                                                int* __restrict__ bsum, int n){
  __shared__ int ws[16];
  int tid = threadIdx.x;
  int gid = blockIdx.x*1024 + tid;
  int v = (gid < n) ? deg[gid] : 0;
  int lane = tid & 63, wid = tid >> 6;
  int s = v;
  for (int off = 1; off < 64; off <<= 1){
    int t2 = __shfl_up(s, off);
    if (lane >= off) s += t2;
  }
  if (lane == 63) ws[wid] = s;
  __syncthreads();
  if (wid == 0){
    int w = (lane < 16) ? ws[lane] : 0;
    for (int off = 1; off < 16; off <<= 1){
      int t2 = __shfl_up(w, off);
      if (lane >= off) w += t2;
    }
    if (lane < 16) ws[lane] = w;
  }
  __syncthreads();
  int base = wid > 0 ? ws[wid-1] : 0;
  int incl = base + s;
  if (gid < n) out[gid] = incl - v;
  if (tid == 1023) bsum[blockIdx.x] = incl;
}

__global__ void k_scan2(int* __restrict__ bsum, int nb){
  int lane = threadIdx.x;  // 64
  int carry = 0;
  for (int base = 0; base < nb; base += 64){
    int i = base + lane;
    int v = (i < nb) ? bsum[i] : 0;
    int s = v;
    for (int off = 1; off < 64; off <<= 1){
      int t2 = __shfl_up(s, off);
      if (lane >= off) s += t2;
    }
    if (i < nb) bsum[i] = carry + s - v;
    int tot = __shfl(s, 63);
    carry += tot;
  }
  if (lane == 0) bsum[nb] = carry;
}

__global__ void k_scan3(int* __restrict__ offs, const int* __restrict__ bsum, int n, int nb){
  int gid = blockIdx.x*TPB + threadIdx.x;
  if (gid < n) offs[gid] += bsum[gid >> 10];
  else if (gid == n) offs[n] = bsum[nb];
}

__global__ void k_fill(const int* __restrict__ src, const int* __restrict__ dst,
                       const int* __restrict__ offs, int* __restrict__ cur,
                       int* __restrict__ esrc, int E){
  int t = blockIdx.x*TPB + threadIdx.x;
  if (t >= E) return;
  int d = dst[t];
  int p = offs[d] + atomicAdd(&cur[d], 1);
  esrc[p] = src[t];
}

// ---------------- fp32 -> bf16 ----------------
__global__ void k_tobf16(const float* __restrict__ in, ush* __restrict__ out, int n4){
  int t = blockIdx.x*TPB + threadIdx.x;
  if (t >= n4) return;
  float4 v = *(const float4*)(in + (size_t)t*4);
  ushort4 o;
  o.x = f2b(v.x); o.y = f2b(v.y); o.z = f2b(v.z); o.w = f2b(v.w);
  *(ushort4*)(out + (size_t)t*4) = o;
}

// weight prep: WT[n][k] = bf16( k<C1 ? wr[k][n] : wl[k-C1][n] ), n in [0,128)
__global__ void k_wprep(const float* __restrict__ wr, const float* __restrict__ wl,
                        int C1, int K, ush* __restrict__ WT){
  int t = blockIdx.x*TPB + threadIdx.x;
  if (t >= 128*K) return;
  int n = t / K, k = t % K;
  float v = (k < C1) ? wr[(size_t)k*128 + n] : wl[(size_t)(k - C1)*128 + n];
  WT[t] = f2b(v);
}

// ---------------- mean aggregation via bf16 gather -> bf16 mean (unroll-4 MLP) ----------------
template<int C>
__global__ __launch_bounds__(256) void k_gather_mean_b(
    const int* __restrict__ offs, const int* __restrict__ esrc,
    const uint_t* __restrict__ xb, uint_t* __restrict__ meanb, int n){
  constexpr int L = C/2;
  int tid = threadIdx.x;
  int nid = blockIdx.x*(256/L) + tid/L;
  int l = tid % L;
  if (nid >= n) return;
  int k0 = offs[nid], k1 = offs[nid+1];
  float s0 = 0.f, s1 = 0.f;
  int k = k0;
  for (; k + 4 <= k1; k += 4){
    int e0 = esrc[k], e1 = esrc[k+1], e2 = esrc[k+2], e3 = esrc[k+3];
    uint_t u0 = xb[(size_t)e0*L + l];
    uint_t u1 = xb[(size_t)e1*L + l];
    uint_t u2 = xb[(size_t)e2*L + l];
    uint_t u3 = xb[(size_t)e3*L + l];
    s0 += b2f((ush)(u0 & 0xffffu)) + b2f((ush)(u1 & 0xffffu))
        + b2f((ush)(u2 & 0xffffu)) + b2f((ush)(u3 & 0xffffu));
    s1 += b2f((ush)(u0 >> 16)) + b2f((ush)(u1 >> 16))
        + b2f((ush)(u2 >> 16)) + b2f((ush)(u3 >> 16));
  }
  for (; k < k1; ++k){
    uint_t u = xb[(size_t)esrc[k]*L + l];
    s0 += b2f((ush)(u & 0xffffu));
    s1 += b2f((ush)(u >> 16));
  }
  float inv = 1.f / (float)max(k1 - k0, 1);
  uint_t lo = f2b(s0*inv), hi = f2b(s1*inv);
  meanb[(size_t)nid*L + l] = lo | (hi << 16);
}

// ---------------- MFMA node matmul: out = [A1|A2] @ W, fused epilogue ----------------
template<int K, bool BN, bool RES, bool RELU>
__global__ __launch_bounds__(256) void k_mm_mfma(
    const ush* __restrict__ A1, int C1,
    const ush* __restrict__ A2,
    const ush* __restrict__ WT,            // [128][K] bf16
    const float* __restrict__ bias,
    const float* __restrict__ bnp, int bnoff,
    const float* __restrict__ res,
    float* __restrict__ out, ush* __restrict__ outb, int n)
{
  constexpr int PAD = K + 8;
  __shared__ ush sA[32][PAD];
  int tid = threadIdx.x;
  int wave = tid >> 6, lane = tid & 63;
  int node0 = blockIdx.x * 32;
  int C2 = K - C1;

  for (int idx = tid; idx < 32*(K/8); idx += 256) {
    int r  = idx / (K/8);
    int kc = (idx % (K/8)) * 8;
    int g = node0 + r;
    uint4 v = make_uint4(0,0,0,0);
    if (g < n) {
      if (kc < C1) v = *(const uint4*)(A1 + (size_t)g*C1 + kc);
      else         v = *(const uint4*)(A2 + (size_t)g*C2 + (kc - C1));
    }
    *(uint4*)&sA[r][kc] = v;
  }
  __syncthreads();

  f32x4 acc[2][2] = {};
  int l15 = lane & 15, lk = (lane >> 4) * 8;
  const ush* wt0 = WT + (size_t)(wave*32 + l15) * K + lk;
  const ush* wt1 = wt0 + (size_t)16 * K;

  #pragma unroll
  for (int kk = 0; kk < K; kk += 32) {
    bf16x8 a0 = *(const bf16x8*)&sA[l15][kk + lk];
    bf16x8 a1 = *(const bf16x8*)&sA[16 + l15][kk + lk];
    bf16x8 b0 = *(const bf16x8*)(wt0 + kk);
    bf16x8 b1 = *(const bf16x8*)(wt1 + kk);
    acc[0][0] = __builtin_amdgcn_mfma_f32_16x16x32_bf16(a0, b0, acc[0][0], 0, 0, 0);
    acc[0][1] = __builtin_amdgcn_mfma_f32_16x16x32_bf16(a0, b1, acc[0][1], 0, 0, 0);
    acc[1][0] = __builtin_amdgcn_mfma_f32_16x16x32_bf16(a1, b0, acc[1][0], 0, 0, 0);
    acc[1][1] = __builtin_amdgcn_mfma_f32_16x16x32_bf16(a1, b1, acc[1][1], 0, 0, 0);
  }

  int r0 = (lane >> 4) * 4;
  #pragma unroll
  for (int mt = 0; mt < 2; ++mt) {
    #pragma unroll
    for (int nt = 0; nt < 2; ++nt) {
      int nn = wave*32 + nt*16 + l15;
      float bv = bias ? bias[nn] : 0.f;
      float sc = 1.f, sh = 0.f;
      if constexpr (BN) { sc = bnp[bnoff + nn]; sh = bnp[bnoff + 128 + nn]; }
      #pragma unroll
      for (int j = 0; j < 4; ++j) {
        int g = node0 + mt*16 + r0 + j;
        if (g < n) {
          float v = acc[mt][nt][j] + bv;
          if constexpr (BN)   v = v*sc + sh;
          if constexpr (RES)  v += res[(size_t)g*128 + nn];
          if constexpr (RELU) v = fmaxf(v, 0.f);
          if (out)  out[(size_t)g*128 + nn] = v;
          if (outb) outb[(size_t)g*128 + nn] = f2b(v);
        }
      }
    }
  }
}

// ---------------- GAT ----------------
__global__ void k_attn(const uint_t* __restrict__ hgb, const float* __restrict__ atts,
                       const float* __restrict__ attd, float* __restrict__ asrc,
                       float* __restrict__ adst, int n){
  int t = blockIdx.x*TPB + threadIdx.x;
  if (t >= n*4) return;
  int nid = t >> 2, h = t & 3;
  const uint_t* hp = hgb + (size_t)nid*64 + h*16;
  float as = 0.f, ad = 0.f;
  #pragma unroll
  for (int i = 0; i < 16; ++i) {
    uint_t u = hp[i];
    float v0 = b2f((ush)(u & 0xffffu));
    float v1 = b2f((ush)(u >> 16));
    as = fmaf(v0, atts[h*32 + 2*i],     as);
    as = fmaf(v1, atts[h*32 + 2*i + 1], as);
    ad = fmaf(v0, attd[h*32 + 2*i],     ad);
    ad = fmaf(v1, attd[h*32 + 2*i + 1], ad);
  }
  asrc[t] = as; adst[t] = ad;
}

// fused: softmax gather (no max shift; logits O(1)) + head-mean + bias + classifier MLP.
// One wave per node. Lane owns hgb channel pair (2l,2l+1); after head-mean, lanes<16
// park emb in LDS (same-wave, no barrier), then lane j computes MLP hidden unit j.
__global__ __launch_bounds__(256) void k_gat(
    const int* __restrict__ offs, const int* __restrict__ esrc,
    const float* __restrict__ asrc, const float* __restrict__ adst,
    const uint_t* __restrict__ hgb, const float* __restrict__ gbias,
    const float* __restrict__ w1, const float* __restrict__ b1,
    const float* __restrict__ w2, const float* __restrict__ b2,
    float* __restrict__ out_emb, float* __restrict__ out_log, int n){
  __shared__ float semb[4][32];
  int tid = threadIdx.x;
  int wl = tid >> 6;
  int l = tid & 63;
  int nid = blockIdx.x*4 + wl;
  if (nid >= n) return;
  int h = l >> 4;
  int i4 = nid*4 + h;
  float ad = adst[i4];
  float e0 = eexp(lrelu(asrc[i4] + ad));                 // self-loop
  uint_t u = hgb[(size_t)nid*64 + l];
  float accD  = e0;
  float accN0 = e0 * b2f((ush)(u & 0xffffu));
  float accN1 = e0 * b2f((ush)(u >> 16));
  int k0 = offs[nid], k1 = offs[nid+1];
  int k = k0;
  for (; k + 4 <= k1; k += 4){
    int s0 = esrc[k], s1 = esrc[k+1], s2 = esrc[k+2], s3 = esrc[k+3];
    float a0 = asrc[s0*4 + h], a1 = asrc[s1*4 + h];
    float a2 = asrc[s2*4 + h], a3 = asrc[s3*4 + h];
    uint_t v0 = hgb[(size_t)s0*64 + l];
    uint_t v1 = hgb[(size_t)s1*64 + l];
    uint_t v2 = hgb[(size_t)s2*64 + l];
    uint_t v3 = hgb[(size_t)s3*64 + l];
    float e0_ = eexp(lrelu(a0 + ad));
    float e1_ = eexp(lrelu(a1 + ad));
    float e2_ = eexp(lrelu(a2 + ad));
    float e3_ = eexp(lrelu(a3 + ad));
    accD += (e0_ + e1_) + (e2_ + e3_);
    accN0 = fmaf(e0_, b2f((ush)(v0 & 0xffffu)), accN0);
    accN0 = fmaf(e1_, b2f((ush)(v1 & 0xffffu)), accN0);
    accN0 = fmaf(e2_, b2f((ush)(v2 & 0xffffu)), accN0);
    accN0 = fmaf(e3_, b2f((ush)(v3 & 0xffffu)), accN0);
    accN1 = fmaf(e0_, b2f((ush)(v0 >> 16)), accN1);
    accN1 = fmaf(e1_, b2f((ush)(v1 >> 16)), accN1);
    accN1 = fmaf(e2_, b2f((ush)(v2 >> 16)), accN1);
    accN1 = fmaf(e3_, b2f((ush)(v3 >> 16)), accN1);
  }
  for (; k < k1; ++k){
    int s = esrc[k];
    float e = eexp(lrelu(asrc[s*4 + h] + ad));
    uint_t v = hgb[(size_t)s*64 + l];
    accD += e;
    accN0 = fmaf(e, b2f((ush)(v & 0xffffu)), accN0);
    accN1 = fmaf(e, b2f((ush)(v >> 16)),     accN1);
  }
  float inv = 1.f / accD;
  float v0 = accN0 * inv, v1 = accN1 * inv;
  // head-mean: lanes {l, l^16, l^32, l^48} hold the 4 heads of channel pair (2(l&15))
  v0 += __shfl_xor(v0, 16); v0 += __shfl_xor(v0, 32);
  v1 += __shfl_xor(v1, 16); v1 += __shfl_xor(v1, 32);
  if (l < 16){
    int c = l*2;
    float2 o;
    o.x = 0.25f*v0 + gbias[c];
    o.y = 0.25f*v1 + gbias[c+1];
    *(float2*)(out_emb + (size_t)nid*32 + c) = o;
    semb[wl][c] = o.x;
    semb[wl][c+1] = o.y;
  }
  // classifier MLP: lane j = hidden unit j (same-wave LDS dependency, no barrier)
  float a = b1[l];
  #pragma unroll
  for (int c = 0; c < 32; ++c) a = fmaf(semb[wl][c], w1[c*64 + l], a);
  float t = fmaxf(a, 0.f) * w2[l];
  t += __shfl_xor(t, 1);  t += __shfl_xor(t, 2);  t += __shfl_xor(t, 4);
  t += __shfl_xor(t, 8);  t += __shfl_xor(t, 16); t += __shfl_xor(t, 32);
  if (l == 0) out_log[nid] = t + b2[0];
}

extern "C" void kernel_launch(void* const* d_in, const int* in_sizes, int n_in,
                              void* d_out, int out_size, void* d_ws, size_t ws_size,
                              hipStream_t stream) {
  const float* x    = (const float*)d_in[0];
  const int*   ei   = (const int*)  d_in[1];
  const float* s1wl = (const float*)d_in[2];
  const float* s1bl = (const float*)d_in[3];
  const float* s1wr = (const float*)d_in[4];
  const float* bn1g = (const float*)d_in[5];
  const float* bn1b = (const float*)d_in[6];
  const float* bn1m = (const float*)d_in[7];
  const float* bn1v = (const float*)d_in[8];
  const float* s2wl = (const float*)d_in[9];
  const float* s2bl = (const float*)d_in[10];
  const float* s2wr = (const float*)d_in[11];
  const float* bn2g = (const float*)d_in[12];
  const float* bn2b = (const float*)d_in[13];
  const float* bn2m = (const float*)d_in[14];
  const float* bn2v = (const float*)d_in[15];
  const float* gatw = (const float*)d_in[16];
  const float* atts = (const float*)d_in[17];
  const float* attd = (const float*)d_in[18];
  const float* gatb = (const float*)d_in[19];
  const float* cw1  = (const float*)d_in[20];
  const float* cb1  = (const float*)d_in[21];
  const float* cw2  = (const float*)d_in[22];
  const float* cb2  = (const float*)d_in[23];

  const int N = in_sizes[0] / 64;
  const int E = in_sizes[1] / 2;
  const int* src = ei;
  const int* dst = ei + E;
  const int NBK = (N + 1023) / 1024;

  // ---- workspace layout (lifetime-aliased, ~69 MB) ----
  float* h1   = (float*)d_ws;            // [N*128] fp32 (residual)
  float* asrc = h1 + (size_t)N*128;      // [N*4]
  float* adst = asrc + (size_t)N*4;      // [N*4]
  float* bnp  = adst + (size_t)N*4;      // [512]
  ush* regA = (ush*)(bnp + 512);         // [N*128] : xb(N*64) + mean1b(N*64) -> mean2b(N*128)
  ush* regB = regA + (size_t)N*128;      // [N*128] : h1b -> hgb
  ush* regC = regB + (size_t)N*128;      // [N*128] : h2b
  ush* W1T  = regC + (size_t)N*128;      // [128*128]
  ush* W2T  = W1T + 128*128;             // [128*256]
  ush* WGT  = W2T + 128*256;             // [128*128]
  int* degi = (int*)(WGT + 128*128);     // [N]
  int* offs = degi + N;                  // [N+1]
  int* cur  = offs + N + 1;              // [N]
  int* esrc = cur + N;                   // [E]
  int* bsum = esrc + E;                  // [NBK+1]

  ush* xb     = regA;                    // [N*64]
  ush* mean1b = regA + (size_t)N*64;     // [N*64]
  ush* mean2b = regA;                    // [N*128] (xb/mean1b dead)
  ush* h1b    = regB;                    // [N*128]
  ush* hgb    = regB;                    // [N*128] (h1b dead after SAGE2 mm)
  ush* h2b    = regC;                    // [N*128]

  float* out_emb = (float*)d_out;
  float* out_log = out_emb + (size_t)N*32;

  hipMemsetAsync(degi, 0, (size_t)N*4, stream);
  hipMemsetAsync(cur,  0, (size_t)N*4, stream);

  k_bnfold<<<1, 256, 0, stream>>>(bn1g,bn1b,bn1m,bn1v, bn2g,bn2b,bn2m,bn2v, bnp);

  // CSR build
  k_deg<<<(E+TPB-1)/TPB, TPB, 0, stream>>>(dst, degi, E);
  k_scan1<<<NBK, 1024, 0, stream>>>(degi, offs, bsum, N);
  k_scan2<<<1, 64, 0, stream>>>(bsum, NBK);
  k_scan3<<<(N+1+TPB-1)/TPB, TPB, 0, stream>>>(offs, bsum, N, NBK);
  k_fill<<<(E+TPB-1)/TPB, TPB, 0, stream>>>(src, dst, offs, cur, esrc, E);

  // weight prep (bf16, transposed+stacked)
  k_wprep<<<(128*128+TPB-1)/TPB, TPB, 0, stream>>>(s1wr, s1wl, 64, 128, W1T);
  k_wprep<<<(128*256+TPB-1)/TPB, TPB, 0, stream>>>(s2wr, s2wl, 128, 256, W2T);
  k_wprep<<<(128*128+TPB-1)/TPB, TPB, 0, stream>>>(gatw, nullptr, 128, 128, WGT);

  k_tobf16<<<(N*16+TPB-1)/TPB, TPB, 0, stream>>>(x, xb, N*16);

  int nmm = (N + 31) / 32;

  // SAGE1: mean1b = gather(xb); h1 = relu(bn([xb|mean1b]@W1 + b1)); h1b = bf16(h1)
  k_gather_mean_b<64><<<(N+7)/8, 256, 0, stream>>>(offs, esrc, (const uint_t*)xb, (uint_t*)mean1b, N);
  k_mm_mfma<128,true,false,true><<<nmm, 256, 0, stream>>>(
      xb, 64, mean1b, W1T, s1bl, bnp, 0, nullptr, h1, h1b, N);

  // SAGE2: mean2b = gather(h1b); h2b = bf16(relu(bn([h1b|mean2b]@W2 + b2) + h1))
  k_gather_mean_b<128><<<(N+3)/4, 256, 0, stream>>>(offs, esrc, (const uint_t*)h1b, (uint_t*)mean2b, N);
  k_mm_mfma<256,true,true,true><<<nmm, 256, 0, stream>>>(
      h1b, 128, mean2b, W2T, s2bl, bnp, 256, h1, nullptr, h2b, N);

  // GAT: hgb = bf16(h2b @ Wg)
  k_mm_mfma<128,false,false,false><<<nmm, 256, 0, stream>>>(
      h2b, 128, nullptr, WGT, nullptr, bnp, 0, nullptr, nullptr, hgb, N);

  k_attn<<<(N*4+TPB-1)/TPB, TPB, 0, stream>>>((const uint_t*)hgb, atts, attd, asrc, adst, N);
  k_gat<<<(N+3)/4, 256, 0, stream>>>(offs, esrc, asrc, adst, (const uint_t*)hgb, gatb,
                                     cw1, cb1, cw2, cb2, out_emb, out_log, N);
}